// Round 8
// baseline (133.631 us; speedup 1.0000x reference)
//
#include <hip/hip_runtime.h>
#include <hip/hip_fp16.h>

#define R_ 3
#define D_ 7            // 2R+1
#define W_ 49
#define N_ 128
#define K_ 131
#define C_ 21
#define B_ 2
#define NN (N_ * N_)
#define TI_ 8                   // tile rows
#define TJ_ 16                  // tile cols
#define PROWS (TI_ + 2 * R_)    // 14
#define PCOLS (TJ_ + 2 * R_)    // 22
#define PSTR 24                 // LDS row stride (32-bit words)
#define NELEM (PROWS * PCOLS)   // 308 staged elements
#define LDSP (PROWS * PSTR + 8) // 344 words (spare write slot at 340)
#define KC 8                    // k-chunks per tile
#define KCHUNK ((K_ + KC - 1) / KC)    // 17
#define HCELLS (PROWS * PCOLS)  // 308 halo cells for gather
#define NSLOT 28                // 28 packed half2 words per pixel (7u x 4s)

typedef __fp16 h2 __attribute__((ext_vector_type(2)));

static __device__ __forceinline__ unsigned h2u(h2 x) { return __builtin_bit_cast(unsigned, x); }
static __device__ __forceinline__ h2 u2h(unsigned x) { return __builtin_bit_cast(h2, x); }

#if defined(__has_builtin)
#if __has_builtin(__builtin_amdgcn_fdot2)
#define FDOT2(a, b, c) __builtin_amdgcn_fdot2((a), (b), (c), false)
#endif
#endif
#ifndef FDOT2
#define FDOT2(a, b, c) ((c) + (float)(a)[0] * (float)(b)[0] + (float)(a)[1] * (float)(b)[1])
#endif

// ---------------------------------------------------------------------------
// R8: R7 (slices + 2-deep prefetch, 55.5us) + ONE change: barrier density
// 2/k -> 0.5/k. Two channels per iteration staged into one of TWO buffer
// sets (4 channel-buffers, 5.5KB LDS): store chA(k)+chB(k+1) into set p,
// ONE __syncthreads, taps(k);taps(k+1), flip set. Single-barrier safety:
// a store to set q at iter t+1 is after that thread's SYNC(t); every
// thread's last READ of set q (iter t-1) is before its SYNC(t); the
// barrier (drains lgkmcnt) separates them. Prefetch distance stays ~2 k.
// Tap math / k-order of accumulation / epilogue / gather byte-identical.
// ---------------------------------------------------------------------------
__global__ __launch_bounds__(256) void rwn_affinity_s(
    const float* __restrict__ feats,   // [B,K,N,N]
    const int*   __restrict__ mask,    // [B,N,N]
    const float* __restrict__ cp,      // [K]
    unsigned* __restrict__ Asl)        // [KC,B,28,NN] packed half2 slices
{
    __shared__ unsigned patchw[2 * 2 * LDSP];  // [set][ch][LDSP]

    const int tile = blockIdx.x;           // 0..127 (16x8 tiles of 8x16)
    const int kc   = blockIdx.y;
    const int b    = blockIdx.z;
    const int tr = tile >> 3, tc = tile & 7;
    const int ti0 = tr * TI_, tj0 = tc * TJ_;

    const int tid = threadIdx.x;
    const int pix = tid >> 1;              // 0..127
    const int h   = tid & 1;               // column-half owner (v = 4h + s)
    const int ti = pix >> 4;               // 0..7
    const int tj = pix & 15;               // 0..15
    const int gi = ti0 + ti, gj = tj0 + tj;

    // ---- hoisted staging setup: thread owns elements tid and 256+tid ----
    const float LOG2E = 1.4426950408889634f;
    int   soff[2];      // clamped global offset
    float swt[2];       // in-bounds * mask * log2e
    float ozw[2];       // 0 for OOB (store zero word), 1 otherwise
    int   slds[2];      // word index in LDS (within a channel buffer)
    #pragma unroll
    for (int r = 0; r < 2; ++r) {
        int e = tid + r * 256;
        bool act = (e < NELEM);
        int pr = e / PCOLS, pc = e - pr * PCOLS;
        int mi = ti0 + pr - R_, mj = tj0 + pc - R_;
        bool inb = act && mi >= 0 && mi < N_ && mj >= 0 && mj < N_;
        int cmi = mi < 0 ? 0 : (mi > N_ - 1 ? N_ - 1 : mi);
        int cmj = mj < 0 ? 0 : (mj > N_ - 1 ? N_ - 1 : mj);
        soff[r] = cmi * N_ + cmj;
        swt[r]  = inb ? ((float)mask[b * NN + soff[r]] * LOG2E) : 0.f;
        ozw[r]  = inb ? 1.f : 0.f;
        slds[r] = act ? (pr * PSTR + pc) : (PROWS * PSTR + 4);  // spare slot
    }

    // phantom kill: h=1's 4th tap lane1 is v=7 (reads REAL staged data)
    const h2 ph2 = h ? (h2){(__fp16)1.f, (__fp16)0.f}
                     : (h2){(__fp16)1.f, (__fp16)1.f};
    const h2 one2 = (h2){(__fp16)1.f, (__fp16)1.f};
    const int cbase = (ti + R_) * PSTR + (tj + R_);  // center word
    const int bh = ti * PSTR + tj + 4 * h;           // row-u tap base (u=0)

    h2 Aacc[14];
    #pragma unroll
    for (int i = 0; i < 14; ++i) Aacc[i] = (h2){(__fp16)0.f, (__fp16)0.f};

    const int k0 = kc * KCHUNK;
    const int k1 = (k0 + KCHUNK < K_) ? (k0 + KCHUNK) : K_;
    const float* fb = feats + (size_t)b * K_ * NN;

    // zero-init all words once: pad cols / spare slots stay 0 forever
    for (int e = tid; e < 2 * 2 * LDSP; e += 256) patchw[e] = 0u;

    // ---- prologue: a* holds k0, b* holds k0+1 (KCHUNK >= 2 always) ----
    float a0, a1, b0 = 0.f, b1 = 0.f;
    {
        const float* f = fb + (size_t)k0 * NN;
        a0 = f[soff[0]] * swt[0];
        a1 = f[soff[1]] * swt[1];
    }
    if (k0 + 1 < k1) {
        const float* f = fb + (size_t)(k0 + 1) * NN;
        b0 = f[soff[0]] * swt[0];
        b1 = f[soff[1]] * swt[1];
    }

    __syncthreads();   // zero-init visible before first staging store

    // tap body (packed fp16, identical math to R5/R6/R7)
    auto taps = [&](const unsigned* buf, float cpk) {
        const unsigned cw = buf[cbase];
        const h2 cE2 = u2h(__builtin_amdgcn_perm(cw, cw, 0x01000100u));
        const h2 cI2 = u2h(__builtin_amdgcn_perm(cw, cw, 0x03020302u));
        h2 ex[14];
        float dsum = 0.f;
        #pragma unroll
        for (int u = 0; u < D_; ++u) {
            const int rb = bh + u * PSTR;
            const unsigned w0 = buf[rb];
            const unsigned w1 = buf[rb + 1];
            const unsigned w2 = buf[rb + 2];
            const unsigned w3 = buf[rb + 3];
            const h2 E01 = u2h(__builtin_amdgcn_perm(w1, w0, 0x05040100u));
            const h2 I01 = u2h(__builtin_amdgcn_perm(w1, w0, 0x07060302u));
            const h2 E23 = u2h(__builtin_amdgcn_perm(w3, w2, 0x05040100u));
            const h2 I23 = u2h(__builtin_amdgcn_perm(w3, w2, 0x07060302u));
            h2 t01 = __builtin_elementwise_max(cE2 * I01, E01 * cI2);
            h2 t23 = __builtin_elementwise_max(cE2 * I23, E23 * cI2);
            t23 = t23 * ph2;               // kill phantom v=7 (h=1 only)
            dsum = FDOT2(t01, one2, dsum);
            dsum = FDOT2(t23, one2, dsum);
            ex[u * 2]     = t01;
            ex[u * 2 + 1] = t23;
        }
        const float denom = dsum + __shfl_xor(dsum, 1, 64);  // lane pair = pixel
        const float scale = cpk * __frcp_rn(denom);          // denom >= 1
        const h2 s2 = __builtin_amdgcn_cvt_pkrtz(scale, scale);
        #pragma unroll
        for (int m = 0; m < 14; ++m) Aacc[m] = ex[m] * s2 + Aacc[m];
    };

    int k = k0;
    int set = 0;
    for (; k + 1 < k1; k += 2) {
        unsigned* sA = patchw + (set * 2 + 0) * LDSP;
        unsigned* sB = patchw + (set * 2 + 1) * LDSP;
        // stage both channels of this pair
        sA[slds[0]] = h2u(__builtin_amdgcn_cvt_pkrtz(ozw[0] * exp2f(a0),
                                                     ozw[0] * exp2f(-a0)));
        sA[slds[1]] = h2u(__builtin_amdgcn_cvt_pkrtz(ozw[1] * exp2f(a1),
                                                     ozw[1] * exp2f(-a1)));
        sB[slds[0]] = h2u(__builtin_amdgcn_cvt_pkrtz(ozw[0] * exp2f(b0),
                                                     ozw[0] * exp2f(-b0)));
        sB[slds[1]] = h2u(__builtin_amdgcn_cvt_pkrtz(ozw[1] * exp2f(b1),
                                                     ozw[1] * exp2f(-b1)));
        // prefetch next pair (issue-to-use distance ~2 k-times)
        if (k + 2 < k1) {
            const float* f = fb + (size_t)(k + 2) * NN;
            a0 = f[soff[0]] * swt[0];
            a1 = f[soff[1]] * swt[1];
        }
        if (k + 3 < k1) {
            const float* f = fb + (size_t)(k + 3) * NN;
            b0 = f[soff[0]] * swt[0];
            b1 = f[soff[1]] * swt[1];
        }
        __syncthreads();               // ONE barrier per 2 channels
        taps(sA, cp[k]);
        taps(sB, cp[k + 1]);
        set ^= 1;
    }
    if (k < k1) {   // odd tail (KCHUNK=17): a* holds the last k
        unsigned* sA = patchw + (set * 2 + 0) * LDSP;
        sA[slds[0]] = h2u(__builtin_amdgcn_cvt_pkrtz(ozw[0] * exp2f(a0),
                                                     ozw[0] * exp2f(-a0)));
        sA[slds[1]] = h2u(__builtin_amdgcn_cvt_pkrtz(ozw[1] * exp2f(a1),
                                                     ozw[1] * exp2f(-a1)));
        __syncthreads();
        taps(sA, cp[k]);
    }

    // ---- epilogue: PLAIN stores of packed Aacc into this kc's slice ----
    const int mk = mask[b * NN + gi * N_ + gj];
    const h2 z2 = (h2){(__fp16)0.f, (__fp16)0.f};
    const int pixg = gi * N_ + gj;
    unsigned* ab = Asl + ((size_t)(kc * B_ + b) * NSLOT) * NN + pixg;
    #pragma unroll
    for (int u = 0; u < D_; ++u) {
        #pragma unroll
        for (int m = 0; m < 2; ++m) {
            const h2 tv = mk ? Aacc[u * 2 + m] : z2;   // unmasked rows -> 0
            ab[(size_t)(u * 4 + 2 * h + m) * NN] = h2u(tv);
        }
    }
}

// Gather (kept from R6): tiled, LDS-staged x2 halo, quad split, coalesced
// store; reads the KC packed-fp16 slices and sums them in f32.
__global__ __launch_bounds__(512) void rwn_gather_s(
    const unsigned* __restrict__ Asl,  // [KC,B,28,NN] packed half2
    const float* __restrict__ x2,      // [B,C,NN]
    float* __restrict__ out)           // [B,NN,C]
{
    __shared__ float x2h[C_ * HCELLS];   // [c][cell], cell=pr*22+pc; 25.9KB

    const int tile = blockIdx.x;     // 0..127: 16 tile-rows x 8 tile-cols
    const int b    = blockIdx.y;
    const int tr = tile >> 3, tc = tile & 7;
    const int gi0 = tr * TI_, gj0 = tc * TJ_;

    const int tid = threadIdx.x;

    // ---- stage x2 halo (zero-filled OOB) ----
    const float* xb = x2 + (size_t)b * C_ * NN;
    for (int e = tid; e < C_ * HCELLS; e += 512) {
        const int c = e / HCELLS, cell = e - c * HCELLS;
        const int pr = cell / PCOLS, pc = cell - pr * PCOLS;
        const int mi = gi0 + pr - R_, mj = gj0 + pc - R_;
        const bool inb = (mi >= 0 && mi < N_ && mj >= 0 && mj < N_);
        const int cmi = mi < 0 ? 0 : (mi > N_ - 1 ? N_ - 1 : mi);
        const int cmj = mj < 0 ? 0 : (mj > N_ - 1 ? N_ - 1 : mj);
        x2h[e] = inb ? xb[c * NN + cmi * N_ + cmj] : 0.f;
    }
    __syncthreads();

    const int h = tid & 3;           // tap-group within quad
    const int q = tid >> 2;          // 0..127 local pixel
    const int qi = q >> 4, qj = q & 15;
    const int gi = gi0 + qi, gj = gj0 + qj;

    // ---- batch the ~13 A taps: per tap sum KC slices in f32 ----
    float av[13];
    int   cells[13];
    #pragma unroll
    for (int idx = 0; idx < 13; ++idx) {
        int w = h + 4 * idx;
        const float valid0 = (w < W_) ? 1.f : 0.f;
        if (w >= W_) w = 0;          // clamp for address safety
        const int u = w / D_, vv = w - u * D_;
        const int s = vv >> 1, ln = vv & 1;
        const int pi = gi + R_ - u, pj = gj + R_ - vv;
        const int cmi = pi < 0 ? 0 : (pi > N_ - 1 ? N_ - 1 : pi);
        const int cmj = pj < 0 ? 0 : (pj > N_ - 1 ? N_ - 1 : pj);
        const float valid = (pi >= 0 && pi < N_ && pj >= 0 && pj < N_)
                          ? valid0 : 0.f;
        const int p = cmi * N_ + cmj;
        const size_t wordoff = (size_t)(u * 4 + s) * NN + p;
        float alo = 0.f, ahi = 0.f;
        #pragma unroll
        for (int kc = 0; kc < KC; ++kc) {
            const h2 pr2 = u2h(Asl[((size_t)(kc * B_ + b) * NSLOT) * NN + wordoff]);
            alo += (float)pr2[0];
            ahi += (float)pr2[1];
        }
        av[idx]    = valid * (ln ? ahi : alo);
        cells[idx] = (qi + 2 * R_ - u) * PCOLS + (qj + 2 * R_ - vv);
    }

    // ---- accumulate 21 channels (LDS reads: stride-1 across lanes) ----
    float acc[C_];
    #pragma unroll
    for (int c = 0; c < C_; ++c) acc[c] = 0.f;
    #pragma unroll
    for (int idx = 0; idx < 13; ++idx) {
        const float a = av[idx];
        const float* xc = x2h + cells[idx];
        #pragma unroll
        for (int c = 0; c < C_; ++c)
            acc[c] += a * xc[c * HCELLS];
    }

    // ---- quad butterfly merge ----
    #pragma unroll
    for (int c = 0; c < C_; ++c) {
        acc[c] += __shfl_xor(acc[c], 1, 64);
        acc[c] += __shfl_xor(acc[c], 2, 64);
    }

    // ---- restage to LDS, then fully coalesced store ----
    __syncthreads();                 // x2h dead; reuse as out staging
    if (h == 0) {
        float* os = x2h + q * C_;    // stride 21 words -> conflict-free
        #pragma unroll
        for (int c = 0; c < C_; ++c) os[c] = acc[c];
    }
    __syncthreads();
    for (int e = tid; e < TI_ * TJ_ * C_; e += 512) {
        const int qq = e / C_, cc = e - qq * C_;
        const int gq = (gi0 + (qq >> 4)) * N_ + gj0 + (qq & 15);
        out[((size_t)b * NN + gq) * C_ + cc] = x2h[e];
    }
}

// ============================================================================
// Legacy fallback path (exact R5 kernels): used only if ws_size < 29.4 MB.
// ============================================================================
__global__ __launch_bounds__(256) void rwn_affinity_at(
    const float* __restrict__ feats, const int* __restrict__ mask,
    const float* __restrict__ cp, float* __restrict__ Aout)
{
    __shared__ unsigned patchw[LDSP];
    const int tile = blockIdx.x, kc = blockIdx.y, b = blockIdx.z;
    const int tr = tile >> 3, tc = tile & 7;
    const int ti0 = tr * TI_, tj0 = tc * TJ_;
    const int tid = threadIdx.x;
    const int pix = tid >> 1, h = tid & 1;
    const int ti = pix >> 4, tj = pix & 15;
    const int gi = ti0 + ti, gj = tj0 + tj;
    const float LOG2E = 1.4426950408889634f;
    int soff[2]; float swt[2]; float ozw[2]; int slds[2];
    #pragma unroll
    for (int r = 0; r < 2; ++r) {
        int e = tid + r * 256;
        bool act = (e < NELEM);
        int pr = e / PCOLS, pc = e - pr * PCOLS;
        int mi = ti0 + pr - R_, mj = tj0 + pc - R_;
        bool inb = act && mi >= 0 && mi < N_ && mj >= 0 && mj < N_;
        int cmi = mi < 0 ? 0 : (mi > N_ - 1 ? N_ - 1 : mi);
        int cmj = mj < 0 ? 0 : (mj > N_ - 1 ? N_ - 1 : mj);
        soff[r] = cmi * N_ + cmj;
        swt[r]  = inb ? ((float)mask[b * NN + soff[r]] * LOG2E) : 0.f;
        ozw[r]  = inb ? 1.f : 0.f;
        slds[r] = act ? (pr * PSTR + pc) : (PROWS * PSTR + 4);
    }
    const h2 ph2 = h ? (h2){(__fp16)1.f, (__fp16)0.f}
                     : (h2){(__fp16)1.f, (__fp16)1.f};
    const h2 one2 = (h2){(__fp16)1.f, (__fp16)1.f};
    const int cbase = (ti + R_) * PSTR + (tj + R_);
    const int bh = ti * PSTR + tj + 4 * h;
    h2 Aacc[14];
    #pragma unroll
    for (int i = 0; i < 14; ++i) Aacc[i] = (h2){(__fp16)0.f, (__fp16)0.f};
    const int k0 = kc * KCHUNK;
    const int k1 = (k0 + KCHUNK < K_) ? (k0 + KCHUNK) : K_;
    const float* fb = feats + (size_t)b * K_ * NN;
    for (int e = tid; e < LDSP; e += 256) patchw[e] = 0u;
    const float* fk0 = fb + (size_t)k0 * NN;
    float pre0 = fk0[soff[0]] * swt[0];
    float pre1 = fk0[soff[1]] * swt[1];
    __syncthreads();
    for (int k = k0; k < k1; ++k) {
        patchw[slds[0]] = h2u(__builtin_amdgcn_cvt_pkrtz(ozw[0] * exp2f(pre0),
                                                         ozw[0] * exp2f(-pre0)));
        patchw[slds[1]] = h2u(__builtin_amdgcn_cvt_pkrtz(ozw[1] * exp2f(pre1),
                                                         ozw[1] * exp2f(-pre1)));
        float n0 = 0.f, n1 = 0.f;
        if (k + 1 < k1) {
            const float* fn = fb + (size_t)(k + 1) * NN;
            n0 = fn[soff[0]] * swt[0];
            n1 = fn[soff[1]] * swt[1];
        }
        __syncthreads();
        const unsigned cw = patchw[cbase];
        const h2 cE2 = u2h(__builtin_amdgcn_perm(cw, cw, 0x01000100u));
        const h2 cI2 = u2h(__builtin_amdgcn_perm(cw, cw, 0x03020302u));
        h2 ex[14];
        float dsum = 0.f;
        #pragma unroll
        for (int u = 0; u < D_; ++u) {
            const int rb = bh + u * PSTR;
            const unsigned w0 = patchw[rb];
            const unsigned w1 = patchw[rb + 1];
            const unsigned w2 = patchw[rb + 2];
            const unsigned w3 = patchw[rb + 3];
            const h2 E01 = u2h(__builtin_amdgcn_perm(w1, w0, 0x05040100u));
            const h2 I01 = u2h(__builtin_amdgcn_perm(w1, w0, 0x07060302u));
            const h2 E23 = u2h(__builtin_amdgcn_perm(w3, w2, 0x05040100u));
            const h2 I23 = u2h(__builtin_amdgcn_perm(w3, w2, 0x07060302u));
            h2 t01 = __builtin_elementwise_max(cE2 * I01, E01 * cI2);
            h2 t23 = __builtin_elementwise_max(cE2 * I23, E23 * cI2);
            t23 = t23 * ph2;
            dsum = FDOT2(t01, one2, dsum);
            dsum = FDOT2(t23, one2, dsum);
            ex[u * 2]     = t01;
            ex[u * 2 + 1] = t23;
        }
        const float denom = dsum + __shfl_xor(dsum, 1, 64);
        const float scale = cp[k] * __frcp_rn(denom);
        const h2 s2 = __builtin_amdgcn_cvt_pkrtz(scale, scale);
        #pragma unroll
        for (int m = 0; m < 14; ++m) Aacc[m] = ex[m] * s2 + Aacc[m];
        __syncthreads();
        pre0 = n0; pre1 = n1;
    }
    if (mask[b * NN + gi * N_ + gj] != 0) {
        const int pixg = gi * N_ + gj;
        float* ab = Aout + (size_t)b * W_ * NN + pixg;
        #pragma unroll
        for (int u = 0; u < D_; ++u) {
            #pragma unroll
            for (int m = 0; m < 2; ++m) {
                const h2 tv = Aacc[u * 2 + m];
                const int wbase = u * D_ + 4 * h + 2 * m;
                atomicAdd(ab + (size_t)wbase * NN, (float)tv[0]);
                if (h == 0 || m < 1)
                    atomicAdd(ab + (size_t)(wbase + 1) * NN, (float)tv[1]);
            }
        }
    }
}

__global__ __launch_bounds__(512) void rwn_gather_at(
    const float* __restrict__ Aarr, const float* __restrict__ x2,
    float* __restrict__ out)
{
    __shared__ float x2h[C_ * HCELLS];
    const int tile = blockIdx.x, b = blockIdx.y;
    const int tr = tile >> 3, tc = tile & 7;
    const int gi0 = tr * TI_, gj0 = tc * TJ_;
    const int tid = threadIdx.x;
    const float* xb = x2 + (size_t)b * C_ * NN;
    for (int e = tid; e < C_ * HCELLS; e += 512) {
        const int c = e / HCELLS, cell = e - c * HCELLS;
        const int pr = cell / PCOLS, pc = cell - pr * PCOLS;
        const int mi = gi0 + pr - R_, mj = gj0 + pc - R_;
        const bool inb = (mi >= 0 && mi < N_ && mj >= 0 && mj < N_);
        const int cmi = mi < 0 ? 0 : (mi > N_ - 1 ? N_ - 1 : mi);
        const int cmj = mj < 0 ? 0 : (mj > N_ - 1 ? N_ - 1 : mj);
        x2h[e] = inb ? xb[c * NN + cmi * N_ + cmj] : 0.f;
    }
    __syncthreads();
    const int h = tid & 3;
    const int q = tid >> 2;
    const int qi = q >> 4, qj = q & 15;
    const int gi = gi0 + qi, gj = gj0 + qj;
    const float* Ab = Aarr + (size_t)b * W_ * NN;
    float av[13];
    int   cells[13];
    #pragma unroll
    for (int idx = 0; idx < 13; ++idx) {
        int w = h + 4 * idx;
        const float valid = (w < W_) ? 1.f : 0.f;
        if (w >= W_) w = W_ - 1;
        const int u = w / D_, v = w - u * D_;
        const int pi = gi + R_ - u, pj = gj + R_ - v;
        const int cmi = pi < 0 ? 0 : (pi > N_ - 1 ? N_ - 1 : pi);
        const int cmj = pj < 0 ? 0 : (pj > N_ - 1 ? N_ - 1 : pj);
        av[idx]    = valid * Ab[(size_t)w * NN + cmi * N_ + cmj];
        cells[idx] = (qi + 2 * R_ - u) * PCOLS + (qj + 2 * R_ - v);
    }
    float acc[C_];
    #pragma unroll
    for (int c = 0; c < C_; ++c) acc[c] = 0.f;
    #pragma unroll
    for (int idx = 0; idx < 13; ++idx) {
        const float a = av[idx];
        const float* xc = x2h + cells[idx];
        #pragma unroll
        for (int c = 0; c < C_; ++c)
            acc[c] += a * xc[c * HCELLS];
    }
    #pragma unroll
    for (int c = 0; c < C_; ++c) {
        acc[c] += __shfl_xor(acc[c], 1, 64);
        acc[c] += __shfl_xor(acc[c], 2, 64);
    }
    __syncthreads();
    if (h == 0) {
        float* os = x2h + q * C_;
        #pragma unroll
        for (int c = 0; c < C_; ++c) os[c] = acc[c];
    }
    __syncthreads();
    for (int e = tid; e < TI_ * TJ_ * C_; e += 512) {
        const int qq = e / C_, cc = e - qq * C_;
        const int gq = (gi0 + (qq >> 4)) * N_ + gj0 + (qq & 15);
        out[((size_t)b * NN + gq) * C_ + cc] = x2h[e];
    }
}

extern "C" void kernel_launch(void* const* d_in, const int* in_sizes, int n_in,
                              void* d_out, int out_size, void* d_ws, size_t ws_size,
                              hipStream_t stream) {
    const float* feats = (const float*)d_in[0];   // [B,K,N,N]
    const float* x2    = (const float*)d_in[1];   // [B,C,NN]
    const int*   mask  = (const int*)d_in[2];     // [B,N,N]
    const float* cp    = (const float*)d_in[3];   // [K]
    float* out = (float*)d_out;

    const size_t need = (size_t)KC * B_ * NSLOT * NN * sizeof(unsigned); // 29.4MB

    if (ws_size >= need) {
        // slices path: no atomics, no memset
        unsigned* Asl = (unsigned*)d_ws;          // [KC,B,28,NN]
        dim3 gridA(128, KC, B_);
        rwn_affinity_s<<<gridA, 256, 0, stream>>>(feats, mask, cp, Asl);
        dim3 gridG(128, B_);
        rwn_gather_s<<<gridG, 512, 0, stream>>>(Asl, x2, out);
    } else {
        // legacy R5 path (ws too small): f32 atomic accumulation
        float* Aarr = (float*)d_ws;               // [B,W,NN] fp32
        const size_t Abytes = (size_t)B_ * W_ * NN * sizeof(float);
        (void)hipMemsetAsync(Aarr, 0, Abytes, stream);
        dim3 gridA(128, KC, B_);
        rwn_affinity_at<<<gridA, 256, 0, stream>>>(feats, mask, cp, Aarr);
        dim3 gridG(128, B_);
        rwn_gather_at<<<gridG, 512, 0, stream>>>(Aarr, x2, out);
    }
}

// Round 9
// 130.110 us; speedup vs baseline: 1.0271x; 1.0271x over previous
//
#include <hip/hip_runtime.h>
#include <hip/hip_fp16.h>

#define R_ 3
#define D_ 7            // 2R+1
#define W_ 49
#define N_ 128
#define K_ 131
#define C_ 21
#define B_ 2
#define NN (N_ * N_)
#define TI_ 8                   // tile rows
#define TJ_ 16                  // tile cols
#define PROWS (TI_ + 2 * R_)    // 14
#define PCOLS (TJ_ + 2 * R_)    // 22
#define PSTR 24                 // LDS row stride (cells)
#define NELEM (PROWS * PCOLS)   // 308 staged elements
#define LDSP (PROWS * PSTR + 8) // 344 cells (spare write slot at 340)
#define KC 6                    // k-chunks per tile (5x22 + 1x21)
#define KCHUNK 22               // legacy-path chunk (ceil 131/6)
#define HCELLS (PROWS * PCOLS)  // 308 halo cells for gather
#define NSLOT 28                // 28 packed half2 words per pixel (7u x 4s)

typedef __fp16 h2 __attribute__((ext_vector_type(2)));
typedef __fp16 h4 __attribute__((ext_vector_type(4)));

static __device__ __forceinline__ unsigned h2u(h2 x) { return __builtin_bit_cast(unsigned, x); }
static __device__ __forceinline__ h2 u2h(unsigned x) { return __builtin_bit_cast(h2, x); }

// ---------------------------------------------------------------------------
// R9: k-PAIR packing. R5 packed two COLUMNS per h2 -> every tap row needed
// 4 v_perm deinterleaves (30/k) and the f32-VALU savings were eaten (Delta0,
// the round's paradox). This version packs two CHANNELS (k, k+1) per h2:
// each halo cell is h4 = (E_k, E_k', I_k, I_k') -> one ds_read_b64 yields
// both operands with ZERO perms, every pk-op computes 2 channels of a tap,
// and the softmax tail (shfl/rcp/scale) runs once per 2 channels. dsum per
// channel stays f32 (per-u fp16 partial of 4 terms, then cvt+add -> no fp16
// overflow). Odd-length chunk tail = dummy channel with cp=0 (exact 0
// contribution). ex[28]+Aacc[28] pushes VGPR to ~78 -> KC 8->6 so grid =
// 1536 = exactly 6 blocks/CU (single residency round; also -25% epilogue/
// gather traffic). Barriers: 2 per pair = 1/k. Prefetch: 1 pair = 2k ahead
// (R7's proven depth). Epilogue/gather layout identical to R6-R8.
// ---------------------------------------------------------------------------
__global__ __launch_bounds__(256) void rwn_affinity_s(
    const float* __restrict__ feats,   // [B,K,N,N]
    const int*   __restrict__ mask,    // [B,N,N]
    const float* __restrict__ cp,      // [K]
    unsigned* __restrict__ Asl)        // [KC,B,28,NN] packed half2 slices
{
    __shared__ h4 patch4[LDSP];        // per cell: (E_k, E_k', I_k, I_k')

    const int tile = blockIdx.x;           // 0..127 (16x8 tiles of 8x16)
    const int kc   = blockIdx.y;
    const int b    = blockIdx.z;
    const int tr = tile >> 3, tc = tile & 7;
    const int ti0 = tr * TI_, tj0 = tc * TJ_;

    const int tid = threadIdx.x;
    const int pix = tid >> 1;              // 0..127
    const int h   = tid & 1;               // column-half owner (v = 4h + e)
    const int ti = pix >> 4;               // 0..7
    const int tj = pix & 15;               // 0..15
    const int gi = ti0 + ti, gj = tj0 + tj;

    // ---- hoisted staging setup: thread owns elements tid and 256+tid ----
    const float LOG2E = 1.4426950408889634f;
    int   soff[2];      // clamped global offset
    float swt[2];       // in-bounds * mask * log2e
    float ozw[2];       // 0 for OOB (store zero cell), 1 otherwise
    int   slds[2];      // cell index in LDS
    #pragma unroll
    for (int r = 0; r < 2; ++r) {
        int e = tid + r * 256;
        bool act = (e < NELEM);
        int pr = e / PCOLS, pc = e - pr * PCOLS;
        int mi = ti0 + pr - R_, mj = tj0 + pc - R_;
        bool inb = act && mi >= 0 && mi < N_ && mj >= 0 && mj < N_;
        int cmi = mi < 0 ? 0 : (mi > N_ - 1 ? N_ - 1 : mi);
        int cmj = mj < 0 ? 0 : (mj > N_ - 1 ? N_ - 1 : mj);
        soff[r] = cmi * N_ + cmj;
        swt[r]  = inb ? ((float)mask[b * NN + soff[r]] * LOG2E) : 0.f;
        ozw[r]  = inb ? 1.f : 0.f;
        slds[r] = act ? (pr * PSTR + pc) : (PROWS * PSTR + 4);  // spare slot
    }

    // phantom: h=1 element 3 is v=7 (reads REAL staged data) -> kill whole pair
    const h2 ph2 = h ? (h2){(__fp16)0.f, (__fp16)0.f}
                     : (h2){(__fp16)1.f, (__fp16)1.f};
    const int cbase = (ti + R_) * PSTR + (tj + R_);  // center cell
    const int bh = ti * PSTR + tj + 4 * h;           // row-u tap base (u=0)

    h2 Aacc[28];        // per tap: (sum over even-k, sum over odd-k)
    #pragma unroll
    for (int i = 0; i < 28; ++i) Aacc[i] = (h2){(__fp16)0.f, (__fp16)0.f};

    // balanced chunks: kc<5 -> 22 channels, kc=5 -> 21
    const int k0 = kc * 22;
    const int k1 = (kc < 5) ? (k0 + 22) : K_;
    const float* fb = feats + (size_t)b * K_ * NN;

    // zero-init all cells once: pad cols 22,23 / spare slot stay 0 forever
    {
        h4 z4 = {};
        for (int e = tid; e < LDSP; e += 256) patch4[e] = z4;
    }

    // ---- prologue: load pair 0 (kA=k0, kB=k0+1; k1-k0 >= 21 so both exist)
    float a0, a1, b0, b1;
    {
        const float* fA = fb + (size_t)k0 * NN;
        const float* fB = fb + (size_t)(k0 + 1) * NN;
        a0 = fA[soff[0]] * swt[0];
        a1 = fA[soff[1]] * swt[1];
        b0 = fB[soff[0]] * swt[0];
        b1 = fB[soff[1]] * swt[1];
    }

    __syncthreads();   // zero-init visible

    const int npair = (k1 - k0 + 1) >> 1;
    for (int p = 0; p < npair; ++p) {
        const int kA = k0 + 2 * p;
        const bool hasB = (kA + 1) < k1;

        // ---- stage this pair: cell = (E_A, E_B, I_A, I_B) ----
        {
            h2 E0 = __builtin_amdgcn_cvt_pkrtz(ozw[0] * exp2f(a0), ozw[0] * exp2f(b0));
            h2 I0 = __builtin_amdgcn_cvt_pkrtz(ozw[0] * exp2f(-a0), ozw[0] * exp2f(-b0));
            h2 E1 = __builtin_amdgcn_cvt_pkrtz(ozw[1] * exp2f(a1), ozw[1] * exp2f(b1));
            h2 I1 = __builtin_amdgcn_cvt_pkrtz(ozw[1] * exp2f(-a1), ozw[1] * exp2f(-b1));
            patch4[slds[0]] = __builtin_shufflevector(E0, I0, 0, 1, 2, 3);
            patch4[slds[1]] = __builtin_shufflevector(E1, I1, 0, 1, 2, 3);
        }

        // ---- prefetch next pair (issue-to-use distance = 2 channels) ----
        {
            const int nA = kA + 2;
            if (nA < k1) {
                const float* f = fb + (size_t)nA * NN;
                a0 = f[soff[0]] * swt[0];
                a1 = f[soff[1]] * swt[1];
            }
            if (nA + 1 < k1) {
                const float* f = fb + (size_t)(nA + 1) * NN;
                b0 = f[soff[0]] * swt[0];
                b1 = f[soff[1]] * swt[1];
            } else { b0 = 0.f; b1 = 0.f; }   // dummy channel (tail)
        }

        __syncthreads();   // pair staged

        // ---- taps: 28 taps x 2 channels, zero perms ----
        const h4 cc = patch4[cbase];
        const h2 cE = __builtin_shufflevector(cc, cc, 0, 1);
        const h2 cI = __builtin_shufflevector(cc, cc, 2, 3);
        h2 ex[28];
        float dsA = 0.f, dsB = 0.f;
        #pragma unroll
        for (int u = 0; u < D_; ++u) {
            const int rb = bh + u * PSTR;
            const h4 n0 = patch4[rb];
            const h4 n1 = patch4[rb + 1];
            const h4 n2 = patch4[rb + 2];
            const h4 n3 = patch4[rb + 3];
            h2 t0 = __builtin_elementwise_max(
                cE * __builtin_shufflevector(n0, n0, 2, 3),
                __builtin_shufflevector(n0, n0, 0, 1) * cI);
            h2 t1 = __builtin_elementwise_max(
                cE * __builtin_shufflevector(n1, n1, 2, 3),
                __builtin_shufflevector(n1, n1, 0, 1) * cI);
            h2 t2 = __builtin_elementwise_max(
                cE * __builtin_shufflevector(n2, n2, 2, 3),
                __builtin_shufflevector(n2, n2, 0, 1) * cI);
            h2 t3 = __builtin_elementwise_max(
                cE * __builtin_shufflevector(n3, n3, 2, 3),
                __builtin_shufflevector(n3, n3, 0, 1) * cI);
            t3 = t3 * ph2;                 // kill phantom v=7 (h=1 only)
            const h2 part = (t0 + t1) + (t2 + t3);   // <= 4*e^9 < fp16 max
            dsA += (float)part[0];
            dsB += (float)part[1];
            ex[u * 4 + 0] = t0;
            ex[u * 4 + 1] = t1;
            ex[u * 4 + 2] = t2;
            ex[u * 4 + 3] = t3;
        }
        const float dA = dsA + __shfl_xor(dsA, 1, 64);   // lane pair = pixel
        const float dB = dsB + __shfl_xor(dsB, 1, 64);
        const float sA = cp[kA] * __frcp_rn(dA);         // denom >= ~1
        const float sB = (hasB ? cp[kA + 1] : 0.f) * __frcp_rn(dB);
        const h2 s2 = __builtin_amdgcn_cvt_pkrtz(sA, sB);
        #pragma unroll
        for (int m = 0; m < 28; ++m) Aacc[m] = ex[m] * s2 + Aacc[m];

        __syncthreads();   // done reading before next pair's stores
    }

    // ---- epilogue: combine channel halves in f32, pack, plain stores ----
    const int mk = mask[b * NN + gi * N_ + gj];
    const float fm = mk ? 1.f : 0.f;
    const int pixg = gi * N_ + gj;
    unsigned* ab = Asl + ((size_t)(kc * B_ + b) * NSLOT) * NN + pixg;
    #pragma unroll
    for (int u = 0; u < D_; ++u) {
        #pragma unroll
        for (int m = 0; m < 2; ++m) {
            const h2 pa = Aacc[u * 4 + 2 * m];
            const h2 pb = Aacc[u * 4 + 2 * m + 1];
            const float vA = fm * ((float)pa[0] + (float)pa[1]);
            const float vB = fm * ((float)pb[0] + (float)pb[1]);
            ab[(size_t)(u * 4 + 2 * h + m) * NN] =
                h2u(__builtin_amdgcn_cvt_pkrtz(vA, vB));
        }
    }
}

// Gather (kept from R6): tiled, LDS-staged x2 halo, quad split, coalesced
// store; reads the KC packed-fp16 slices and sums them in f32.
__global__ __launch_bounds__(512) void rwn_gather_s(
    const unsigned* __restrict__ Asl,  // [KC,B,28,NN] packed half2
    const float* __restrict__ x2,      // [B,C,NN]
    float* __restrict__ out)           // [B,NN,C]
{
    __shared__ float x2h[C_ * HCELLS];   // [c][cell], cell=pr*22+pc; 25.9KB

    const int tile = blockIdx.x;     // 0..127: 16 tile-rows x 8 tile-cols
    const int b    = blockIdx.y;
    const int tr = tile >> 3, tc = tile & 7;
    const int gi0 = tr * TI_, gj0 = tc * TJ_;

    const int tid = threadIdx.x;

    // ---- stage x2 halo (zero-filled OOB) ----
    const float* xb = x2 + (size_t)b * C_ * NN;
    for (int e = tid; e < C_ * HCELLS; e += 512) {
        const int c = e / HCELLS, cell = e - c * HCELLS;
        const int pr = cell / PCOLS, pc = cell - pr * PCOLS;
        const int mi = gi0 + pr - R_, mj = gj0 + pc - R_;
        const bool inb = (mi >= 0 && mi < N_ && mj >= 0 && mj < N_);
        const int cmi = mi < 0 ? 0 : (mi > N_ - 1 ? N_ - 1 : mi);
        const int cmj = mj < 0 ? 0 : (mj > N_ - 1 ? N_ - 1 : mj);
        x2h[e] = inb ? xb[c * NN + cmi * N_ + cmj] : 0.f;
    }
    __syncthreads();

    const int h = tid & 3;           // tap-group within quad
    const int q = tid >> 2;          // 0..127 local pixel
    const int qi = q >> 4, qj = q & 15;
    const int gi = gi0 + qi, gj = gj0 + qj;

    // ---- batch the ~13 A taps: per tap sum KC slices in f32 ----
    float av[13];
    int   cells[13];
    #pragma unroll
    for (int idx = 0; idx < 13; ++idx) {
        int w = h + 4 * idx;
        const float valid0 = (w < W_) ? 1.f : 0.f;
        if (w >= W_) w = 0;          // clamp for address safety
        const int u = w / D_, vv = w - u * D_;
        const int s = vv >> 1, ln = vv & 1;
        const int pi = gi + R_ - u, pj = gj + R_ - vv;
        const int cmi = pi < 0 ? 0 : (pi > N_ - 1 ? N_ - 1 : pi);
        const int cmj = pj < 0 ? 0 : (pj > N_ - 1 ? N_ - 1 : pj);
        const float valid = (pi >= 0 && pi < N_ && pj >= 0 && pj < N_)
                          ? valid0 : 0.f;
        const int p = cmi * N_ + cmj;
        const size_t wordoff = (size_t)(u * 4 + s) * NN + p;
        float alo = 0.f, ahi = 0.f;
        #pragma unroll
        for (int kc = 0; kc < KC; ++kc) {
            const h2 pr2 = u2h(Asl[((size_t)(kc * B_ + b) * NSLOT) * NN + wordoff]);
            alo += (float)pr2[0];
            ahi += (float)pr2[1];
        }
        av[idx]    = valid * (ln ? ahi : alo);
        cells[idx] = (qi + 2 * R_ - u) * PCOLS + (qj + 2 * R_ - vv);
    }

    // ---- accumulate 21 channels (LDS reads: stride-1 across lanes) ----
    float acc[C_];
    #pragma unroll
    for (int c = 0; c < C_; ++c) acc[c] = 0.f;
    #pragma unroll
    for (int idx = 0; idx < 13; ++idx) {
        const float a = av[idx];
        const float* xc = x2h + cells[idx];
        #pragma unroll
        for (int c = 0; c < C_; ++c)
            acc[c] += a * xc[c * HCELLS];
    }

    // ---- quad butterfly merge ----
    #pragma unroll
    for (int c = 0; c < C_; ++c) {
        acc[c] += __shfl_xor(acc[c], 1, 64);
        acc[c] += __shfl_xor(acc[c], 2, 64);
    }

    // ---- restage to LDS, then fully coalesced store ----
    __syncthreads();                 // x2h dead; reuse as out staging
    if (h == 0) {
        float* os = x2h + q * C_;    // stride 21 words -> conflict-free
        #pragma unroll
        for (int c = 0; c < C_; ++c) os[c] = acc[c];
    }
    __syncthreads();
    for (int e = tid; e < TI_ * TJ_ * C_; e += 512) {
        const int qq = e / C_, cc = e - qq * C_;
        const int gq = (gi0 + (qq >> 4)) * N_ + gj0 + (qq & 15);
        out[((size_t)b * NN + gq) * C_ + cc] = x2h[e];
    }
}

// ============================================================================
// Legacy fallback path (R5-style atomics): used only if ws_size < 22 MB.
// Correct for any KC/KCHUNK covering K exactly (6x22 clamps at 131).
// ============================================================================
__global__ __launch_bounds__(256) void rwn_affinity_at(
    const float* __restrict__ feats, const int* __restrict__ mask,
    const float* __restrict__ cp, float* __restrict__ Aout)
{
    __shared__ unsigned patchw[LDSP];
    const int tile = blockIdx.x, kc = blockIdx.y, b = blockIdx.z;
    const int tr = tile >> 3, tc = tile & 7;
    const int ti0 = tr * TI_, tj0 = tc * TJ_;
    const int tid = threadIdx.x;
    const int pix = tid >> 1, h = tid & 1;
    const int ti = pix >> 4, tj = pix & 15;
    const int gi = ti0 + ti, gj = tj0 + tj;
    const float LOG2E = 1.4426950408889634f;
    int soff[2]; float swt[2]; float ozw[2]; int slds[2];
    #pragma unroll
    for (int r = 0; r < 2; ++r) {
        int e = tid + r * 256;
        bool act = (e < NELEM);
        int pr = e / PCOLS, pc = e - pr * PCOLS;
        int mi = ti0 + pr - R_, mj = tj0 + pc - R_;
        bool inb = act && mi >= 0 && mi < N_ && mj >= 0 && mj < N_;
        int cmi = mi < 0 ? 0 : (mi > N_ - 1 ? N_ - 1 : mi);
        int cmj = mj < 0 ? 0 : (mj > N_ - 1 ? N_ - 1 : mj);
        soff[r] = cmi * N_ + cmj;
        swt[r]  = inb ? ((float)mask[b * NN + soff[r]] * LOG2E) : 0.f;
        ozw[r]  = inb ? 1.f : 0.f;
        slds[r] = act ? (pr * PSTR + pc) : (PROWS * PSTR + 4);
    }
    const h2 ph2 = h ? (h2){(__fp16)1.f, (__fp16)0.f}
                     : (h2){(__fp16)1.f, (__fp16)1.f};
    const int cbase = (ti + R_) * PSTR + (tj + R_);
    const int bh = ti * PSTR + tj + 4 * h;
    h2 Aacc[14];
    #pragma unroll
    for (int i = 0; i < 14; ++i) Aacc[i] = (h2){(__fp16)0.f, (__fp16)0.f};
    const int k0 = kc * KCHUNK;
    const int k1 = (k0 + KCHUNK < K_) ? (k0 + KCHUNK) : K_;
    const float* fb = feats + (size_t)b * K_ * NN;
    for (int e = tid; e < LDSP; e += 256) patchw[e] = 0u;
    const float* fk0 = fb + (size_t)k0 * NN;
    float pre0 = fk0[soff[0]] * swt[0];
    float pre1 = fk0[soff[1]] * swt[1];
    __syncthreads();
    for (int k = k0; k < k1; ++k) {
        patchw[slds[0]] = h2u(__builtin_amdgcn_cvt_pkrtz(ozw[0] * exp2f(pre0),
                                                         ozw[0] * exp2f(-pre0)));
        patchw[slds[1]] = h2u(__builtin_amdgcn_cvt_pkrtz(ozw[1] * exp2f(pre1),
                                                         ozw[1] * exp2f(-pre1)));
        float n0 = 0.f, n1 = 0.f;
        if (k + 1 < k1) {
            const float* fn = fb + (size_t)(k + 1) * NN;
            n0 = fn[soff[0]] * swt[0];
            n1 = fn[soff[1]] * swt[1];
        }
        __syncthreads();
        const unsigned cw = patchw[cbase];
        const h2 cE2 = u2h(__builtin_amdgcn_perm(cw, cw, 0x01000100u));
        const h2 cI2 = u2h(__builtin_amdgcn_perm(cw, cw, 0x03020302u));
        h2 ex[14];
        float dsum = 0.f;
        #pragma unroll
        for (int u = 0; u < D_; ++u) {
            const int rb = bh + u * PSTR;
            const unsigned w0 = patchw[rb];
            const unsigned w1 = patchw[rb + 1];
            const unsigned w2 = patchw[rb + 2];
            const unsigned w3 = patchw[rb + 3];
            const h2 E01 = u2h(__builtin_amdgcn_perm(w1, w0, 0x05040100u));
            const h2 I01 = u2h(__builtin_amdgcn_perm(w1, w0, 0x07060302u));
            const h2 E23 = u2h(__builtin_amdgcn_perm(w3, w2, 0x05040100u));
            const h2 I23 = u2h(__builtin_amdgcn_perm(w3, w2, 0x07060302u));
            h2 t01 = __builtin_elementwise_max(cE2 * I01, E01 * cI2);
            h2 t23 = __builtin_elementwise_max(cE2 * I23, E23 * cI2);
            t23 = t23 * ph2;
            dsum += (float)t01[0] + (float)t01[1];
            dsum += (float)t23[0] + (float)t23[1];
            ex[u * 2]     = t01;
            ex[u * 2 + 1] = t23;
        }
        const float denom = dsum + __shfl_xor(dsum, 1, 64);
        const float scale = cp[k] * __frcp_rn(denom);
        const h2 s2 = __builtin_amdgcn_cvt_pkrtz(scale, scale);
        #pragma unroll
        for (int m = 0; m < 14; ++m) Aacc[m] = ex[m] * s2 + Aacc[m];
        __syncthreads();
        pre0 = n0; pre1 = n1;
    }
    if (mask[b * NN + gi * N_ + gj] != 0) {
        const int pixg = gi * N_ + gj;
        float* ab = Aout + (size_t)b * W_ * NN + pixg;
        #pragma unroll
        for (int u = 0; u < D_; ++u) {
            #pragma unroll
            for (int m = 0; m < 2; ++m) {
                const h2 tv = Aacc[u * 2 + m];
                const int wbase = u * D_ + 4 * h + 2 * m;
                atomicAdd(ab + (size_t)wbase * NN, (float)tv[0]);
                if (h == 0 || m < 1)
                    atomicAdd(ab + (size_t)(wbase + 1) * NN, (float)tv[1]);
            }
        }
    }
}

__global__ __launch_bounds__(512) void rwn_gather_at(
    const float* __restrict__ Aarr, const float* __restrict__ x2,
    float* __restrict__ out)
{
    __shared__ float x2h[C_ * HCELLS];
    const int tile = blockIdx.x, b = blockIdx.y;
    const int tr = tile >> 3, tc = tile & 7;
    const int gi0 = tr * TI_, gj0 = tc * TJ_;
    const int tid = threadIdx.x;
    const float* xb = x2 + (size_t)b * C_ * NN;
    for (int e = tid; e < C_ * HCELLS; e += 512) {
        const int c = e / HCELLS, cell = e - c * HCELLS;
        const int pr = cell / PCOLS, pc = cell - pr * PCOLS;
        const int mi = gi0 + pr - R_, mj = gj0 + pc - R_;
        const bool inb = (mi >= 0 && mi < N_ && mj >= 0 && mj < N_);
        const int cmi = mi < 0 ? 0 : (mi > N_ - 1 ? N_ - 1 : mi);
        const int cmj = mj < 0 ? 0 : (mj > N_ - 1 ? N_ - 1 : mj);
        x2h[e] = inb ? xb[c * NN + cmi * N_ + cmj] : 0.f;
    }
    __syncthreads();
    const int h = tid & 3;
    const int q = tid >> 2;
    const int qi = q >> 4, qj = q & 15;
    const int gi = gi0 + qi, gj = gj0 + qj;
    const float* Ab = Aarr + (size_t)b * W_ * NN;
    float av[13];
    int   cells[13];
    #pragma unroll
    for (int idx = 0; idx < 13; ++idx) {
        int w = h + 4 * idx;
        const float valid = (w < W_) ? 1.f : 0.f;
        if (w >= W_) w = W_ - 1;
        const int u = w / D_, v = w - u * D_;
        const int pi = gi + R_ - u, pj = gj + R_ - v;
        const int cmi = pi < 0 ? 0 : (pi > N_ - 1 ? N_ - 1 : pi);
        const int cmj = pj < 0 ? 0 : (pj > N_ - 1 ? N_ - 1 : pj);
        av[idx]    = valid * Ab[(size_t)w * NN + cmi * N_ + cmj];
        cells[idx] = (qi + 2 * R_ - u) * PCOLS + (qj + 2 * R_ - v);
    }
    float acc[C_];
    #pragma unroll
    for (int c = 0; c < C_; ++c) acc[c] = 0.f;
    #pragma unroll
    for (int idx = 0; idx < 13; ++idx) {
        const float a = av[idx];
        const float* xc = x2h + cells[idx];
        #pragma unroll
        for (int c = 0; c < C_; ++c)
            acc[c] += a * xc[c * HCELLS];
    }
    #pragma unroll
    for (int c = 0; c < C_; ++c) {
        acc[c] += __shfl_xor(acc[c], 1, 64);
        acc[c] += __shfl_xor(acc[c], 2, 64);
    }
    __syncthreads();
    if (h == 0) {
        float* os = x2h + q * C_;
        #pragma unroll
        for (int c = 0; c < C_; ++c) os[c] = acc[c];
    }
    __syncthreads();
    for (int e = tid; e < TI_ * TJ_ * C_; e += 512) {
        const int qq = e / C_, cc = e - qq * C_;
        const int gq = (gi0 + (qq >> 4)) * N_ + gj0 + (qq & 15);
        out[((size_t)b * NN + gq) * C_ + cc] = x2h[e];
    }
}

extern "C" void kernel_launch(void* const* d_in, const int* in_sizes, int n_in,
                              void* d_out, int out_size, void* d_ws, size_t ws_size,
                              hipStream_t stream) {
    const float* feats = (const float*)d_in[0];   // [B,K,N,N]
    const float* x2    = (const float*)d_in[1];   // [B,C,NN]
    const int*   mask  = (const int*)d_in[2];     // [B,N,N]
    const float* cp    = (const float*)d_in[3];   // [K]
    float* out = (float*)d_out;

    const size_t need = (size_t)KC * B_ * NSLOT * NN * sizeof(unsigned); // 22MB

    if (ws_size >= need) {
        // slices path: no atomics, no memset
        unsigned* Asl = (unsigned*)d_ws;          // [KC,B,28,NN]
        dim3 gridA(128, KC, B_);
        rwn_affinity_s<<<gridA, 256, 0, stream>>>(feats, mask, cp, Asl);
        dim3 gridG(128, B_);
        rwn_gather_s<<<gridG, 512, 0, stream>>>(Asl, x2, out);
    } else {
        // legacy path (ws too small): f32 atomic accumulation
        float* Aarr = (float*)d_ws;               // [B,W,NN] fp32
        const size_t Abytes = (size_t)B_ * W_ * NN * sizeof(float);
        (void)hipMemsetAsync(Aarr, 0, Abytes, stream);
        dim3 gridA(128, KC, B_);
        rwn_affinity_at<<<gridA, 256, 0, stream>>>(feats, mask, cp, Aarr);
        dim3 gridG(128, B_);
        rwn_gather_at<<<gridG, 512, 0, stream>>>(Aarr, x2, out);
    }
}